// Round 8
// baseline (417.357 us; speedup 1.0000x reference)
//
#include <hip/hip_runtime.h>
#include <math.h>

#define BSZ 4
#define NE 40
#define DM 128
#define DR 128
#define NE2 80
#define NROW_BI (NE*NE)       // 1600 rows per (b,i)
#define NBIJ (BSZ*NE*NE)      // 6400
#define BI_CNT (BSZ*NE)       // 160
#define NROWS (BSZ*NE*NE*NE)  // 256000 factor rows

typedef __attribute__((ext_vector_type(8))) short short8;
typedef __attribute__((ext_vector_type(4))) float f32x4;

__device__ __forceinline__ float gelu_exact(float x) {
    return 0.5f * x * (1.0f + erff(x * 0.70710678118654752f));
}

// split f32 -> bf16 hi (truncate) + bf16 lo (truncate of residual).
// dropped lo*lo term ~2^-16 rel; fine at this problem's tolerance.
__device__ __forceinline__ void bf16_split(float x, short& h, short& l) {
    unsigned u = __float_as_uint(x);
    h = (short)(u >> 16);
    float hf = __uint_as_float(u & 0xffff0000u);
    l = (short)(__float_as_uint(x - hf) >> 16);
}

// ---------------------------------------------------------------------------
// K0: pre-split Wc_f^T into bf16 hi/lo (RNE for hi): Wt[e][d] = W_comb[128+d][e]
// 64 blocks x 256 threads, one element each. Output: 2 x 128x128 bf16 (64KB).
// ---------------------------------------------------------------------------
__global__ __launch_bounds__(256)
void k0_wprep(const float* __restrict__ Wcomb, unsigned short* __restrict__ WtHi,
              unsigned short* __restrict__ WtLo) {
    int idx = blockIdx.x * 256 + threadIdx.x;   // 0..16383
    int e = idx >> 7, d = idx & 127;
    float w = Wcomb[(size_t)(DR + d)*DM + e];
    unsigned u = __float_as_uint(w);
    unsigned hb = (u + 0x7fffu + ((u >> 16) & 1u)) >> 16;     // RNE
    float hf = __uint_as_float(hb << 16);
    float r = w - hf;
    unsigned rb = __float_as_uint(r);
    unsigned lb = (rb + 0x7fffu + ((rb >> 16) & 1u)) >> 16;   // RNE
    WtHi[(size_t)e*DM + d] = (unsigned short)hb;
    WtLo[(size_t)e*DM + d] = (unsigned short)lb;
}

// ---------------------------------------------------------------------------
// K1: ht_proj[bi,j,:] = ht[bi,j,:] @ Wc_ht + b_comb   (6400 rows x 128)
// ---------------------------------------------------------------------------
__global__ __launch_bounds__(256, 2)
void k1_htproj(const float* __restrict__ ht, const float* __restrict__ Wcomb,
               const float* __restrict__ bcomb, float* __restrict__ htp) {
    __shared__ float WL[DM*DM];
    __shared__ float rowbuf[16][132];
    const int t = threadIdx.x;
    const int row0 = blockIdx.x * 16;

    const float4* Wsrc4 = (const float4*)Wcomb;   // first 128 rows = Wc_ht
    float4* WL4s = (float4*)WL;
    #pragma unroll
    for (int it = 0; it < 16; ++it) WL4s[it*256 + t] = Wsrc4[it*256 + t];

    const float4* ht4 = (const float4*)ht;
    #pragma unroll
    for (int it = 0; it < 2; ++it) {
        int f4 = it*256 + t; int r = f4 >> 5, q = f4 & 31;
        *(float4*)&rowbuf[r][q*4] = ht4[(size_t)(row0 + r)*32 + q];
    }
    __syncthreads();

    const int tc = t & 15, rs = t >> 4;
    const float4* bc4 = (const float4*)bcomb;
    float4 c0 = bc4[tc], c1 = bc4[16 + tc];
    float acc[8] = {c0.x,c0.y,c0.z,c0.w,c1.x,c1.y,c1.z,c1.w};
    const float4* WL4 = (const float4*)WL;
    #pragma unroll 8
    for (int d = 0; d < DM; ++d) {
        float a = rowbuf[rs][d];
        float4 b0 = WL4[d*32 + tc], b1 = WL4[d*32 + 16 + tc];
        acc[0] = fmaf(a, b0.x, acc[0]); acc[1] = fmaf(a, b0.y, acc[1]);
        acc[2] = fmaf(a, b0.z, acc[2]); acc[3] = fmaf(a, b0.w, acc[3]);
        acc[4] = fmaf(a, b1.x, acc[4]); acc[5] = fmaf(a, b1.y, acc[5]);
        acc[6] = fmaf(a, b1.z, acc[6]); acc[7] = fmaf(a, b1.w, acc[7]);
    }
    float4* o4 = (float4*)htp;
    float4 o0 = {acc[0],acc[1],acc[2],acc[3]}, o1 = {acc[4],acc[5],acc[6],acc[7]};
    o4[(size_t)(row0 + rs)*32 + tc]      = o0;
    o4[(size_t)(row0 + rs)*32 + 16 + tc] = o1;
}

// ---------------------------------------------------------------------------
// K2 (MFMA): per 64-row block tile, 4 independent waves x 16 rows.
// C = factor_rows @ Wc_f via 3-term bf16-split mfma_f32_16x16x32_bf16
// (ah*bh + al*bh + ah*bl), f32 accumulate. No LDS, no barriers.
// A-frag: row=lane&15, k=(lane>>4)*8+0..7 (contiguous f32 load + split).
// B-frag: from pre-split WtHi/WtLo [e][d] (L2-resident, shared by all blocks).
// C-frag: col=lane&15, row=(lane>>4)*4+reg  [m89-verified].
// Epilogue: e1/e2 = sum_d wv[d]*gelu(C+htp_{j,k}[d]); 16-lane shfl reduce;
// mask + dual scatter into energy.
// ---------------------------------------------------------------------------
__global__ __launch_bounds__(256)
void k2_energy(const float* __restrict__ factor,
               const unsigned short* __restrict__ WtHi,
               const unsigned short* __restrict__ WtLo,
               const float* __restrict__ wv, const float* __restrict__ htp,
               const int* __restrict__ entn, float* __restrict__ energy) {
    const int t    = threadIdx.x;
    const int wid  = t >> 6;
    const int lane = t & 63;
    const int c    = lane & 15;        // A-row / C-col / B-col index
    const int g16  = lane >> 4;        // k-group / C-row-group
    const int row0 = blockIdx.x * 64 + wid * 16;

    f32x4 acc[8];
    #pragma unroll
    for (int nf = 0; nf < 8; ++nf) acc[nf] = (f32x4){0.f, 0.f, 0.f, 0.f};

    // wv values for this lane's 8 columns
    float wvv[8];
    #pragma unroll
    for (int nf = 0; nf < 8; ++nf) wvv[nf] = wv[nf*16 + c];

    const float* arow = factor + (size_t)(row0 + c)*128;

    #pragma unroll
    for (int ks = 0; ks < 4; ++ks) {
        const float4* ap = (const float4*)(arow + ks*32 + g16*8);
        float4 a0 = ap[0], a1 = ap[1];
        float av[8] = {a0.x,a0.y,a0.z,a0.w,a1.x,a1.y,a1.z,a1.w};
        short8 ah, al;
        #pragma unroll
        for (int e = 0; e < 8; ++e) {
            short h, l; bf16_split(av[e], h, l);
            ah[e] = h; al[e] = l;
        }
        const int koff = ks*32 + g16*8;
        #pragma unroll
        for (int nf = 0; nf < 8; ++nf) {
            short8 bh = *(const short8*)(WtHi + (size_t)(nf*16 + c)*128 + koff);
            short8 bl = *(const short8*)(WtLo + (size_t)(nf*16 + c)*128 + koff);
            acc[nf] = __builtin_amdgcn_mfma_f32_16x16x32_bf16(ah, bh, acc[nf], 0, 0, 0);
            acc[nf] = __builtin_amdgcn_mfma_f32_16x16x32_bf16(al, bh, acc[nf], 0, 0, 0);
            acc[nf] = __builtin_amdgcn_mfma_f32_16x16x32_bf16(ah, bl, acc[nf], 0, 0, 0);
        }
    }

    const int e0 = entn[0], e1n = entn[1], e2n = entn[2], e3 = entn[3];

    #pragma unroll
    for (int e = 0; e < 4; ++e) {
        int rg  = row0 + g16*4 + e;          // global row this lane holds
        int bi  = rg / NROW_BI;
        int rem = rg - bi*NROW_BI;
        int j = rem / NE;
        int k = rem - j*NE;
        const float* h1 = htp + (size_t)(bi*NE + j)*DM;
        const float* h2 = htp + (size_t)(bi*NE + k)*DM;
        float p1 = 0.0f, p2 = 0.0f;
        #pragma unroll
        for (int nf = 0; nf < 8; ++nf) {
            float cc = acc[nf][e];
            float v1 = h1[nf*16 + c];
            float v2 = h2[nf*16 + c];
            p1 = fmaf(wvv[nf], gelu_exact(cc + v1), p1);
            p2 = fmaf(wvv[nf], gelu_exact(cc + v2), p2);
        }
        p1 += __shfl_xor(p1, 1); p2 += __shfl_xor(p2, 1);
        p1 += __shfl_xor(p1, 2); p2 += __shfl_xor(p2, 2);
        p1 += __shfl_xor(p1, 4); p2 += __shfl_xor(p2, 4);
        p1 += __shfl_xor(p1, 8); p2 += __shfl_xor(p2, 8);
        if (c == 0) {
            int b = bi / NE, i = bi - b*NE;
            int en = (b == 0) ? e0 : (b == 1) ? e1n : (b == 2) ? e2n : e3;
            bool msk = (j == k) || !((i < en) && (j < en) && (k < en));
            float v1 = msk ? -10000.0f : p1;
            float v2 = msk ? -10000.0f : p2;
            energy[(size_t)(bi*NE + j)*NE2 + k]       = v1;
            energy[(size_t)(bi*NE + k)*NE2 + NE + j]  = v2;
        }
    }
}

// ---------------------------------------------------------------------------
// K3: per (b,i,j): softmax over 80 energies, then weighted factor sum.
// ---------------------------------------------------------------------------
__global__ __launch_bounds__(64)
void k3_attn_av(const float* __restrict__ energy, const float* __restrict__ factor,
                float* __restrict__ av) {
    __shared__ float att[NE2];
    const int l = threadIdx.x;
    const int gid = blockIdx.x;
    const int bi = gid % BI_CNT;
    const int j  = gid / BI_CNT;

    const float* eb = energy + (size_t)(bi*NE + j)*NE2;
    float ea = eb[l];
    float ebv = (l < 16) ? eb[64 + l] : -INFINITY;
    float m = fmaxf(ea, ebv);
    m = fmaxf(m, __shfl_xor(m, 1));  m = fmaxf(m, __shfl_xor(m, 2));
    m = fmaxf(m, __shfl_xor(m, 4));  m = fmaxf(m, __shfl_xor(m, 8));
    m = fmaxf(m, __shfl_xor(m, 16)); m = fmaxf(m, __shfl_xor(m, 32));
    float x1 = expf(ea - m);
    float x2 = (l < 16) ? expf(ebv - m) : 0.0f;
    float s = x1 + x2;
    s += __shfl_xor(s, 1);  s += __shfl_xor(s, 2);
    s += __shfl_xor(s, 4);  s += __shfl_xor(s, 8);
    s += __shfl_xor(s, 16); s += __shfl_xor(s, 32);
    att[l] = x1 / s;
    if (l < 16) att[64 + l] = x2 / s;
    __syncthreads();

    float av0 = 0.0f, av1 = 0.0f;
    const float* f1 = factor + (size_t)(bi*NROW_BI + j*NE)*128;
    #pragma unroll 8
    for (int k = 0; k < NE; ++k) {
        float w = att[k];
        av0 = fmaf(w, f1[k*128 + l],      av0);
        av1 = fmaf(w, f1[k*128 + 64 + l], av1);
    }
    const float* f2 = factor + (size_t)(bi*NROW_BI + j)*128;
    #pragma unroll 8
    for (int q = 0; q < NE; ++q) {
        float w = att[NE + q];
        av0 = fmaf(w, f2[(size_t)q*NE*128 + l],      av0);
        av1 = fmaf(w, f2[(size_t)q*NE*128 + 64 + l], av1);
    }
    float* o = av + (size_t)(bi*NE + j)*128;
    o[l] = av0; o[64 + l] = av1;
}

// ---------------------------------------------------------------------------
// K4: out = LN(av @ W_fc + b_fc + ht) * scale + bias.
// ---------------------------------------------------------------------------
__global__ __launch_bounds__(256, 2)
void k4_out(const float* __restrict__ av, const float* __restrict__ Wfc,
            const float* __restrict__ bfc, const float* __restrict__ ht,
            const float* __restrict__ lns, const float* __restrict__ lnb,
            float* __restrict__ out) {
    __shared__ float WL[DM*DR];
    __shared__ float rowbuf[16][132];
    const int t = threadIdx.x;
    const int row0 = blockIdx.x * 16;

    const float4* W4 = (const float4*)Wfc;
    float4* WL4s = (float4*)WL;
    #pragma unroll
    for (int it = 0; it < 16; ++it) WL4s[it*256 + t] = W4[it*256 + t];
    const float4* av4 = (const float4*)av;
    #pragma unroll
    for (int it = 0; it < 2; ++it) {
        int f4 = it*256 + t; int r = f4 >> 5, q = f4 & 31;
        *(float4*)&rowbuf[r][q*4] = av4[(size_t)(row0 + r)*32 + q];
    }
    __syncthreads();

    const int tc = t & 15, rs = t >> 4;
    const int row = row0 + rs;
    const float4* bf4 = (const float4*)bfc;
    float4 c0 = bf4[tc], c1 = bf4[16 + tc];
    float acc[8] = {c0.x,c0.y,c0.z,c0.w,c1.x,c1.y,c1.z,c1.w};
    const float4* WL4 = (const float4*)WL;
    #pragma unroll 8
    for (int d = 0; d < DM; ++d) {
        float a = rowbuf[rs][d];
        float4 b0 = WL4[d*32 + tc], b1 = WL4[d*32 + 16 + tc];
        acc[0] = fmaf(a, b0.x, acc[0]); acc[1] = fmaf(a, b0.y, acc[1]);
        acc[2] = fmaf(a, b0.z, acc[2]); acc[3] = fmaf(a, b0.w, acc[3]);
        acc[4] = fmaf(a, b1.x, acc[4]); acc[5] = fmaf(a, b1.y, acc[5]);
        acc[6] = fmaf(a, b1.z, acc[6]); acc[7] = fmaf(a, b1.w, acc[7]);
    }
    const float4* ht4 = (const float4*)ht;
    float4 ha = ht4[(size_t)row*32 + tc], hb = ht4[(size_t)row*32 + 16 + tc];
    float o[8];
    o[0] = acc[0] + ha.x; o[1] = acc[1] + ha.y; o[2] = acc[2] + ha.z; o[3] = acc[3] + ha.w;
    o[4] = acc[4] + hb.x; o[5] = acc[5] + hb.y; o[6] = acc[6] + hb.z; o[7] = acc[7] + hb.w;

    float s1 = o[0]+o[1]+o[2]+o[3]+o[4]+o[5]+o[6]+o[7];
    s1 += __shfl_xor(s1, 1); s1 += __shfl_xor(s1, 2);
    s1 += __shfl_xor(s1, 4); s1 += __shfl_xor(s1, 8);
    float mu = s1 * (1.0f/128.0f);
    float s2 = 0.0f;
    #pragma unroll
    for (int jj = 0; jj < 8; ++jj) { float d = o[jj] - mu; s2 = fmaf(d, d, s2); }
    s2 += __shfl_xor(s2, 1); s2 += __shfl_xor(s2, 2);
    s2 += __shfl_xor(s2, 4); s2 += __shfl_xor(s2, 8);
    float var = s2 * (1.0f/128.0f);
    float rstd = 1.0f / sqrtf(var + 1e-6f);

    const float4* sc4 = (const float4*)lns;
    const float4* bs4 = (const float4*)lnb;
    float4 sa = sc4[tc], sb = sc4[16 + tc];
    float4 ba = bs4[tc], bb = bs4[16 + tc];
    float4 r0, r1;
    r0.x = (o[0]-mu)*rstd*sa.x + ba.x; r0.y = (o[1]-mu)*rstd*sa.y + ba.y;
    r0.z = (o[2]-mu)*rstd*sa.z + ba.z; r0.w = (o[3]-mu)*rstd*sa.w + ba.w;
    r1.x = (o[4]-mu)*rstd*sb.x + bb.x; r1.y = (o[5]-mu)*rstd*sb.y + bb.y;
    r1.z = (o[6]-mu)*rstd*sb.z + bb.z; r1.w = (o[7]-mu)*rstd*sb.w + bb.w;
    float4* o4 = (float4*)out;
    o4[(size_t)row*32 + tc]      = r0;
    o4[(size_t)row*32 + 16 + tc] = r1;
}

// ---------------------------------------------------------------------------
extern "C" void kernel_launch(void* const* d_in, const int* in_sizes, int n_in,
                              void* d_out, int out_size, void* d_ws, size_t ws_size,
                              hipStream_t stream) {
    const float* ht     = (const float*)d_in[0];
    const float* factor = (const float*)d_in[1];
    const int*   entn   = (const int*)  d_in[2];
    const float* Wcomb  = (const float*)d_in[3];
    const float* bcomb  = (const float*)d_in[4];
    const float* wv     = (const float*)d_in[5];
    const float* Wfc    = (const float*)d_in[6];
    const float* bfc    = (const float*)d_in[7];
    const float* lns    = (const float*)d_in[8];
    const float* lnb    = (const float*)d_in[9];
    float* out = (float*)d_out;

    char* ws = (char*)d_ws;
    float* htp    = (float*)(ws);                       // 6400*128*4 = 3,276,800 B
    float* energy = (float*)(ws + 3276800);             // 6400*80*4  = 2,048,000 B
    float* av     = (float*)(ws + 3276800 + 2048000);   // 6400*128*4 = 3,276,800 B
    // WtHi/WtLo live in the av region (64KB << 3.3MB): K0 writes, K2 reads,
    // K3 overwrites av only after K2 completes (same stream). Re-written
    // every call, so re-poisoning is harmless.
    unsigned short* WtHi = (unsigned short*)av;
    unsigned short* WtLo = (unsigned short*)(av + 16384);

    k0_wprep<<<dim3(64),      dim3(256), 0, stream>>>(Wcomb, WtHi, WtLo);
    k1_htproj<<<dim3(NBIJ/16),dim3(256), 0, stream>>>(ht, Wcomb, bcomb, htp);
    k2_energy<<<dim3(4000),   dim3(256), 0, stream>>>(factor, WtHi, WtLo, wv, htp, entn, energy);
    k3_attn_av<<<dim3(NBIJ),  dim3(64),  0, stream>>>(energy, factor, av);
    k4_out<<<dim3(NBIJ/16),   dim3(256), 0, stream>>>(av, Wfc, bfc, ht, lns, lnb, out);
}

// Round 9
// 335.524 us; speedup vs baseline: 1.2439x; 1.2439x over previous
//
#include <hip/hip_runtime.h>
#include <math.h>

#define BSZ 4
#define NE 40
#define DM 128
#define DR 128
#define NE2 80
#define NROW_BI (NE*NE)       // 1600 rows per (b,i)
#define NBIJ (BSZ*NE*NE)      // 6400
#define BI_CNT (BSZ*NE)       // 160
#define NROWS (BSZ*NE*NE*NE)  // 256000 factor rows

typedef __attribute__((ext_vector_type(8))) short short8;
typedef __attribute__((ext_vector_type(4))) float f32x4;

__device__ __forceinline__ float gelu_exact(float x) {
    return 0.5f * x * (1.0f + erff(x * 0.70710678118654752f));
}

// split f32 -> bf16 hi (truncate) + bf16 lo (truncate of residual).
__device__ __forceinline__ void bf16_split(float x, short& h, short& l) {
    unsigned u = __float_as_uint(x);
    h = (short)(u >> 16);
    float hf = __uint_as_float(u & 0xffff0000u);
    l = (short)(__float_as_uint(x - hf) >> 16);
}

// ---------------------------------------------------------------------------
// K0: pre-split Wc_f^T into bf16 hi/lo (RNE): Wt[e][d] = W_comb[128+d][e]
// ---------------------------------------------------------------------------
__global__ __launch_bounds__(256)
void k0_wprep(const float* __restrict__ Wcomb, unsigned short* __restrict__ WtHi,
              unsigned short* __restrict__ WtLo) {
    int idx = blockIdx.x * 256 + threadIdx.x;   // 0..16383
    int e = idx >> 7, d = idx & 127;
    float w = Wcomb[(size_t)(DR + d)*DM + e];
    unsigned u = __float_as_uint(w);
    unsigned hb = (u + 0x7fffu + ((u >> 16) & 1u)) >> 16;     // RNE
    float hf = __uint_as_float(hb << 16);
    float r = w - hf;
    unsigned rb = __float_as_uint(r);
    unsigned lb = (rb + 0x7fffu + ((rb >> 16) & 1u)) >> 16;   // RNE
    WtHi[(size_t)e*DM + d] = (unsigned short)hb;
    WtLo[(size_t)e*DM + d] = (unsigned short)lb;
}

// ---------------------------------------------------------------------------
// K1: ht_proj[bi,j,:] = ht[bi,j,:] @ Wc_ht + b_comb   (6400 rows x 128)
// ---------------------------------------------------------------------------
__global__ __launch_bounds__(256, 2)
void k1_htproj(const float* __restrict__ ht, const float* __restrict__ Wcomb,
               const float* __restrict__ bcomb, float* __restrict__ htp) {
    __shared__ float WL[DM*DM];
    __shared__ float rowbuf[16][132];
    const int t = threadIdx.x;
    const int row0 = blockIdx.x * 16;

    const float4* Wsrc4 = (const float4*)Wcomb;   // first 128 rows = Wc_ht
    float4* WL4s = (float4*)WL;
    #pragma unroll
    for (int it = 0; it < 16; ++it) WL4s[it*256 + t] = Wsrc4[it*256 + t];

    const float4* ht4 = (const float4*)ht;
    #pragma unroll
    for (int it = 0; it < 2; ++it) {
        int f4 = it*256 + t; int r = f4 >> 5, q = f4 & 31;
        *(float4*)&rowbuf[r][q*4] = ht4[(size_t)(row0 + r)*32 + q];
    }
    __syncthreads();

    const int tc = t & 15, rs = t >> 4;
    const float4* bc4 = (const float4*)bcomb;
    float4 c0 = bc4[tc], c1 = bc4[16 + tc];
    float acc[8] = {c0.x,c0.y,c0.z,c0.w,c1.x,c1.y,c1.z,c1.w};
    const float4* WL4 = (const float4*)WL;
    #pragma unroll 8
    for (int d = 0; d < DM; ++d) {
        float a = rowbuf[rs][d];
        float4 b0 = WL4[d*32 + tc], b1 = WL4[d*32 + 16 + tc];
        acc[0] = fmaf(a, b0.x, acc[0]); acc[1] = fmaf(a, b0.y, acc[1]);
        acc[2] = fmaf(a, b0.z, acc[2]); acc[3] = fmaf(a, b0.w, acc[3]);
        acc[4] = fmaf(a, b1.x, acc[4]); acc[5] = fmaf(a, b1.y, acc[5]);
        acc[6] = fmaf(a, b1.z, acc[6]); acc[7] = fmaf(a, b1.w, acc[7]);
    }
    float4* o4 = (float4*)htp;
    float4 o0 = {acc[0],acc[1],acc[2],acc[3]}, o1 = {acc[4],acc[5],acc[6],acc[7]};
    o4[(size_t)(row0 + rs)*32 + tc]      = o0;
    o4[(size_t)(row0 + rs)*32 + 16 + tc] = o1;
}

// ---------------------------------------------------------------------------
// K2 (MFMA + LDS-B + M_rep=2): 1000 blocks x 512 thr (8 waves), 256 rows/blk,
// 32 rows/wave as two 16-row tiles sharing each B-frag (6 MFMA per ds-pair).
// B staged once per block into LDS, 16B-chunk-transposed:
//   ldschunk(d16,e) = d16*128 + e   (d16 = koff/8, e = output col)
// so a B-frag read is lanes c=0..15 -> consecutive 16B chunks (2-way bank
// alias only = free). Read latency ~120cy LDS vs ~250cy L2 (round-8 failure:
// latency-bound on per-nf L2 loads, MfmaUtil 4.6%).
// ---------------------------------------------------------------------------
__global__ __launch_bounds__(512, 3)
void k2_energy(const float* __restrict__ factor,
               const unsigned short* __restrict__ WtHi,
               const unsigned short* __restrict__ WtLo,
               const float* __restrict__ wv, const float* __restrict__ htp,
               const int* __restrict__ entn, float* __restrict__ energy) {
    __shared__ unsigned short WL[32768];   // 64KB: hi = chunks 0..2047, lo = 2048..4095
    const int t    = threadIdx.x;
    const int wid  = t >> 6;          // 0..7
    const int lane = t & 63;
    const int c    = lane & 15;       // A-row-in-tile / C-col / B-col index
    const int g16  = lane >> 4;       // k-group / C-row-group
    const int row0 = blockIdx.x * 256 + wid * 32;

    // ---- stage Wt hi/lo -> LDS (transposed by 16B chunk) ----
    // global side: consecutive t read contiguous memory (wave reads 1KB runs).
    #pragma unroll
    for (int it = 0; it < 8; ++it) {
        int u = it*512 + t;                 // 0..4095 chunk id
        int m = u & 2047;                   // chunk within one matrix
        int e = m >> 4, d16 = m & 15;
        const unsigned short* src = (it < 4 ? WtHi : WtLo) + (size_t)e*DM + d16*8;
        short8 v = *(const short8*)src;
        int dst = ((it < 4) ? 0 : 2048) + d16*128 + e;
        *(short8*)&WL[(size_t)dst*8] = v;
    }
    __syncthreads();

    f32x4 acc[2][8];
    #pragma unroll
    for (int tile = 0; tile < 2; ++tile)
        #pragma unroll
        for (int nf = 0; nf < 8; ++nf) acc[tile][nf] = (f32x4){0.f,0.f,0.f,0.f};

    float wvv[8];
    #pragma unroll
    for (int nf = 0; nf < 8; ++nf) wvv[nf] = wv[nf*16 + c];

    const float* arow0 = factor + (size_t)(row0 + c)*128;
    const float* arow1 = factor + (size_t)(row0 + 16 + c)*128;

    #pragma unroll
    for (int ks = 0; ks < 4; ++ks) {
        const int off = ks*32 + g16*8;
        float4 a00 = *(const float4*)(arow0 + off);
        float4 a01 = *(const float4*)(arow0 + off + 4);
        float4 a10 = *(const float4*)(arow1 + off);
        float4 a11 = *(const float4*)(arow1 + off + 4);
        float av0[8] = {a00.x,a00.y,a00.z,a00.w,a01.x,a01.y,a01.z,a01.w};
        float av1[8] = {a10.x,a10.y,a10.z,a10.w,a11.x,a11.y,a11.z,a11.w};
        short8 ah0, al0, ah1, al1;
        #pragma unroll
        for (int e = 0; e < 8; ++e) {
            short h, l;
            bf16_split(av0[e], h, l); ah0[e] = h; al0[e] = l;
            bf16_split(av1[e], h, l); ah1[e] = h; al1[e] = l;
        }
        const int cb = (ks*4 + g16)*128;    // chunk base for this koff
        #pragma unroll
        for (int nf = 0; nf < 8; ++nf) {
            short8 bh = *(const short8*)&WL[(size_t)(cb + nf*16 + c)*8];
            short8 bl = *(const short8*)&WL[(size_t)(2048 + cb + nf*16 + c)*8];
            acc[0][nf] = __builtin_amdgcn_mfma_f32_16x16x32_bf16(ah0, bh, acc[0][nf], 0, 0, 0);
            acc[0][nf] = __builtin_amdgcn_mfma_f32_16x16x32_bf16(al0, bh, acc[0][nf], 0, 0, 0);
            acc[0][nf] = __builtin_amdgcn_mfma_f32_16x16x32_bf16(ah0, bl, acc[0][nf], 0, 0, 0);
            acc[1][nf] = __builtin_amdgcn_mfma_f32_16x16x32_bf16(ah1, bh, acc[1][nf], 0, 0, 0);
            acc[1][nf] = __builtin_amdgcn_mfma_f32_16x16x32_bf16(al1, bh, acc[1][nf], 0, 0, 0);
            acc[1][nf] = __builtin_amdgcn_mfma_f32_16x16x32_bf16(ah1, bl, acc[1][nf], 0, 0, 0);
        }
    }

    const int e0 = entn[0], e1n = entn[1], e2n = entn[2], e3 = entn[3];

    #pragma unroll
    for (int tile = 0; tile < 2; ++tile) {
        #pragma unroll
        for (int e = 0; e < 4; ++e) {
            int rg  = row0 + tile*16 + g16*4 + e;   // global row this lane holds
            int bi  = rg / NROW_BI;
            int rem = rg - bi*NROW_BI;
            int j = rem / NE;
            int k = rem - j*NE;
            const float* h1 = htp + (size_t)(bi*NE + j)*DM;
            const float* h2 = htp + (size_t)(bi*NE + k)*DM;
            float p1 = 0.0f, p2 = 0.0f;
            #pragma unroll
            for (int nf = 0; nf < 8; ++nf) {
                float cc = acc[tile][nf][e];
                float v1 = h1[nf*16 + c];
                float v2 = h2[nf*16 + c];
                p1 = fmaf(wvv[nf], gelu_exact(cc + v1), p1);
                p2 = fmaf(wvv[nf], gelu_exact(cc + v2), p2);
            }
            p1 += __shfl_xor(p1, 1); p2 += __shfl_xor(p2, 1);
            p1 += __shfl_xor(p1, 2); p2 += __shfl_xor(p2, 2);
            p1 += __shfl_xor(p1, 4); p2 += __shfl_xor(p2, 4);
            p1 += __shfl_xor(p1, 8); p2 += __shfl_xor(p2, 8);
            if (c == 0) {
                int b = bi / NE, i = bi - b*NE;
                int en = (b == 0) ? e0 : (b == 1) ? e1n : (b == 2) ? e2n : e3;
                bool msk = (j == k) || !((i < en) && (j < en) && (k < en));
                float v1 = msk ? -10000.0f : p1;
                float v2 = msk ? -10000.0f : p2;
                energy[(size_t)(bi*NE + j)*NE2 + k]       = v1;
                energy[(size_t)(bi*NE + k)*NE2 + NE + j]  = v2;
            }
        }
    }
}

// ---------------------------------------------------------------------------
// K3: per (b,i,j): softmax over 80 energies, then weighted factor sum.
// ---------------------------------------------------------------------------
__global__ __launch_bounds__(64)
void k3_attn_av(const float* __restrict__ energy, const float* __restrict__ factor,
                float* __restrict__ av) {
    __shared__ float att[NE2];
    const int l = threadIdx.x;
    const int gid = blockIdx.x;
    const int bi = gid % BI_CNT;
    const int j  = gid / BI_CNT;

    const float* eb = energy + (size_t)(bi*NE + j)*NE2;
    float ea = eb[l];
    float ebv = (l < 16) ? eb[64 + l] : -INFINITY;
    float m = fmaxf(ea, ebv);
    m = fmaxf(m, __shfl_xor(m, 1));  m = fmaxf(m, __shfl_xor(m, 2));
    m = fmaxf(m, __shfl_xor(m, 4));  m = fmaxf(m, __shfl_xor(m, 8));
    m = fmaxf(m, __shfl_xor(m, 16)); m = fmaxf(m, __shfl_xor(m, 32));
    float x1 = expf(ea - m);
    float x2 = (l < 16) ? expf(ebv - m) : 0.0f;
    float s = x1 + x2;
    s += __shfl_xor(s, 1);  s += __shfl_xor(s, 2);
    s += __shfl_xor(s, 4);  s += __shfl_xor(s, 8);
    s += __shfl_xor(s, 16); s += __shfl_xor(s, 32);
    att[l] = x1 / s;
    if (l < 16) att[64 + l] = x2 / s;
    __syncthreads();

    float av0 = 0.0f, av1 = 0.0f;
    const float* f1 = factor + (size_t)(bi*NROW_BI + j*NE)*128;
    #pragma unroll 8
    for (int k = 0; k < NE; ++k) {
        float w = att[k];
        av0 = fmaf(w, f1[k*128 + l],      av0);
        av1 = fmaf(w, f1[k*128 + 64 + l], av1);
    }
    const float* f2 = factor + (size_t)(bi*NROW_BI + j)*128;
    #pragma unroll 8
    for (int q = 0; q < NE; ++q) {
        float w = att[NE + q];
        av0 = fmaf(w, f2[(size_t)q*NE*128 + l],      av0);
        av1 = fmaf(w, f2[(size_t)q*NE*128 + 64 + l], av1);
    }
    float* o = av + (size_t)(bi*NE + j)*128;
    o[l] = av0; o[64 + l] = av1;
}

// ---------------------------------------------------------------------------
// K4: out = LN(av @ W_fc + b_fc + ht) * scale + bias.
// ---------------------------------------------------------------------------
__global__ __launch_bounds__(256, 2)
void k4_out(const float* __restrict__ av, const float* __restrict__ Wfc,
            const float* __restrict__ bfc, const float* __restrict__ ht,
            const float* __restrict__ lns, const float* __restrict__ lnb,
            float* __restrict__ out) {
    __shared__ float WL[DM*DR];
    __shared__ float rowbuf[16][132];
    const int t = threadIdx.x;
    const int row0 = blockIdx.x * 16;

    const float4* W4 = (const float4*)Wfc;
    float4* WL4s = (float4*)WL;
    #pragma unroll
    for (int it = 0; it < 16; ++it) WL4s[it*256 + t] = W4[it*256 + t];
    const float4* av4 = (const float4*)av;
    #pragma unroll
    for (int it = 0; it < 2; ++it) {
        int f4 = it*256 + t; int r = f4 >> 5, q = f4 & 31;
        *(float4*)&rowbuf[r][q*4] = av4[(size_t)(row0 + r)*32 + q];
    }
    __syncthreads();

    const int tc = t & 15, rs = t >> 4;
    const int row = row0 + rs;
    const float4* bf4 = (const float4*)bfc;
    float4 c0 = bf4[tc], c1 = bf4[16 + tc];
    float acc[8] = {c0.x,c0.y,c0.z,c0.w,c1.x,c1.y,c1.z,c1.w};
    const float4* WL4 = (const float4*)WL;
    #pragma unroll 8
    for (int d = 0; d < DM; ++d) {
        float a = rowbuf[rs][d];
        float4 b0 = WL4[d*32 + tc], b1 = WL4[d*32 + 16 + tc];
        acc[0] = fmaf(a, b0.x, acc[0]); acc[1] = fmaf(a, b0.y, acc[1]);
        acc[2] = fmaf(a, b0.z, acc[2]); acc[3] = fmaf(a, b0.w, acc[3]);
        acc[4] = fmaf(a, b1.x, acc[4]); acc[5] = fmaf(a, b1.y, acc[5]);
        acc[6] = fmaf(a, b1.z, acc[6]); acc[7] = fmaf(a, b1.w, acc[7]);
    }
    const float4* ht4 = (const float4*)ht;
    float4 ha = ht4[(size_t)row*32 + tc], hb = ht4[(size_t)row*32 + 16 + tc];
    float o[8];
    o[0] = acc[0] + ha.x; o[1] = acc[1] + ha.y; o[2] = acc[2] + ha.z; o[3] = acc[3] + ha.w;
    o[4] = acc[4] + hb.x; o[5] = acc[5] + hb.y; o[6] = acc[6] + hb.z; o[7] = acc[7] + hb.w;

    float s1 = o[0]+o[1]+o[2]+o[3]+o[4]+o[5]+o[6]+o[7];
    s1 += __shfl_xor(s1, 1); s1 += __shfl_xor(s1, 2);
    s1 += __shfl_xor(s1, 4); s1 += __shfl_xor(s1, 8);
    float mu = s1 * (1.0f/128.0f);
    float s2 = 0.0f;
    #pragma unroll
    for (int jj = 0; jj < 8; ++jj) { float d = o[jj] - mu; s2 = fmaf(d, d, s2); }
    s2 += __shfl_xor(s2, 1); s2 += __shfl_xor(s2, 2);
    s2 += __shfl_xor(s2, 4); s2 += __shfl_xor(s2, 8);
    float var = s2 * (1.0f/128.0f);
    float rstd = 1.0f / sqrtf(var + 1e-6f);

    const float4* sc4 = (const float4*)lns;
    const float4* bs4 = (const float4*)lnb;
    float4 sa = sc4[tc], sb = sc4[16 + tc];
    float4 ba = bs4[tc], bb = bs4[16 + tc];
    float4 r0, r1;
    r0.x = (o[0]-mu)*rstd*sa.x + ba.x; r0.y = (o[1]-mu)*rstd*sa.y + ba.y;
    r0.z = (o[2]-mu)*rstd*sa.z + ba.z; r0.w = (o[3]-mu)*rstd*sa.w + ba.w;
    r1.x = (o[4]-mu)*rstd*sb.x + bb.x; r1.y = (o[5]-mu)*rstd*sb.y + bb.y;
    r1.z = (o[6]-mu)*rstd*sb.z + bb.z; r1.w = (o[7]-mu)*rstd*sb.w + bb.w;
    float4* o4 = (float4*)out;
    o4[(size_t)row*32 + tc]      = r0;
    o4[(size_t)row*32 + 16 + tc] = r1;
}

// ---------------------------------------------------------------------------
extern "C" void kernel_launch(void* const* d_in, const int* in_sizes, int n_in,
                              void* d_out, int out_size, void* d_ws, size_t ws_size,
                              hipStream_t stream) {
    const float* ht     = (const float*)d_in[0];
    const float* factor = (const float*)d_in[1];
    const int*   entn   = (const int*)  d_in[2];
    const float* Wcomb  = (const float*)d_in[3];
    const float* bcomb  = (const float*)d_in[4];
    const float* wv     = (const float*)d_in[5];
    const float* Wfc    = (const float*)d_in[6];
    const float* bfc    = (const float*)d_in[7];
    const float* lns    = (const float*)d_in[8];
    const float* lnb    = (const float*)d_in[9];
    float* out = (float*)d_out;

    char* ws = (char*)d_ws;
    float* htp    = (float*)(ws);                       // 6400*128*4 = 3,276,800 B
    float* energy = (float*)(ws + 3276800);             // 6400*80*4  = 2,048,000 B
    float* av     = (float*)(ws + 3276800 + 2048000);   // 6400*128*4 = 3,276,800 B
    // WtHi/WtLo live in the av region (64KB << 3.3MB): K0 writes, K2 reads,
    // K3 overwrites av only after K2 completes (same stream).
    unsigned short* WtHi = (unsigned short*)av;
    unsigned short* WtLo = (unsigned short*)(av + 16384);

    k0_wprep<<<dim3(64),      dim3(256), 0, stream>>>(Wcomb, WtHi, WtLo);
    k1_htproj<<<dim3(NBIJ/16),dim3(256), 0, stream>>>(ht, Wcomb, bcomb, htp);
    k2_energy<<<dim3(1000),   dim3(512), 0, stream>>>(factor, WtHi, WtLo, wv, htp, entn, energy);
    k3_attn_av<<<dim3(NBIJ),  dim3(64),  0, stream>>>(energy, factor, av);
    k4_out<<<dim3(NBIJ/16),   dim3(256), 0, stream>>>(av, Wfc, bfc, ht, lns, lnb, out);
}

// Round 10
// 302.871 us; speedup vs baseline: 1.3780x; 1.1078x over previous
//
#include <hip/hip_runtime.h>
#include <math.h>

#define BSZ 4
#define NE 40
#define DM 128
#define DR 128
#define NE2 80
#define NROW_BI (NE*NE)       // 1600 rows per (b,i)
#define NBIJ (BSZ*NE*NE)      // 6400
#define BI_CNT (BSZ*NE)       // 160
#define NROWS (BSZ*NE*NE*NE)  // 256000 factor rows

typedef __attribute__((ext_vector_type(8))) short short8;
typedef __attribute__((ext_vector_type(4))) float f32x4;

// Branchless gelu: 0.5x(1+erf(x/sqrt2)), erf via A&S 7.1.26 (|err|<1.5e-7).
// Library erff is ~60-80 instr with divergent range branches (round-9 PMC:
// VALUBusy 64% = ~80us of a 126us kernel); this is ~14 instr, no branches.
__device__ __forceinline__ float gelu_fast(float x) {
    float z  = x * 0.70710678118654752f;
    float az = fabsf(z);
    float t  = __builtin_amdgcn_rcpf(fmaf(0.3275911f, az, 1.0f));
    float p  = fmaf(1.061405429f, t, -1.453152027f);
    p = fmaf(p, t, 1.421413741f);
    p = fmaf(p, t, -0.284496736f);
    p = fmaf(p, t, 0.254829592f);
    float e  = __expf(-az*az);
    float er = fmaf(-p*t, e, 1.0f);          // erf(|z|)
    er = copysignf(er, z);
    return 0.5f * x * (1.0f + er);
}

// split f32 -> bf16 hi (truncate) + bf16 lo (truncate of residual).
__device__ __forceinline__ void bf16_split(float x, short& h, short& l) {
    unsigned u = __float_as_uint(x);
    h = (short)(u >> 16);
    float hf = __uint_as_float(u & 0xffff0000u);
    l = (short)(__float_as_uint(x - hf) >> 16);
}

// ---------------------------------------------------------------------------
// K0: pre-split Wc_f^T into bf16 hi/lo (RNE): Wt[e][d] = W_comb[128+d][e]
// ---------------------------------------------------------------------------
__global__ __launch_bounds__(256)
void k0_wprep(const float* __restrict__ Wcomb, unsigned short* __restrict__ WtHi,
              unsigned short* __restrict__ WtLo) {
    int idx = blockIdx.x * 256 + threadIdx.x;   // 0..16383
    int e = idx >> 7, d = idx & 127;
    float w = Wcomb[(size_t)(DR + d)*DM + e];
    unsigned u = __float_as_uint(w);
    unsigned hb = (u + 0x7fffu + ((u >> 16) & 1u)) >> 16;     // RNE
    float hf = __uint_as_float(hb << 16);
    float r = w - hf;
    unsigned rb = __float_as_uint(r);
    unsigned lb = (rb + 0x7fffu + ((rb >> 16) & 1u)) >> 16;   // RNE
    WtHi[(size_t)e*DM + d] = (unsigned short)hb;
    WtLo[(size_t)e*DM + d] = (unsigned short)lb;
}

// ---------------------------------------------------------------------------
// K1: ht_proj[bi,j,:] = ht[bi,j,:] @ Wc_ht + b_comb   (6400 rows x 128)
// ---------------------------------------------------------------------------
__global__ __launch_bounds__(256, 2)
void k1_htproj(const float* __restrict__ ht, const float* __restrict__ Wcomb,
               const float* __restrict__ bcomb, float* __restrict__ htp) {
    __shared__ float WL[DM*DM];
    __shared__ float rowbuf[16][132];
    const int t = threadIdx.x;
    const int row0 = blockIdx.x * 16;

    const float4* Wsrc4 = (const float4*)Wcomb;   // first 128 rows = Wc_ht
    float4* WL4s = (float4*)WL;
    #pragma unroll
    for (int it = 0; it < 16; ++it) WL4s[it*256 + t] = Wsrc4[it*256 + t];

    const float4* ht4 = (const float4*)ht;
    #pragma unroll
    for (int it = 0; it < 2; ++it) {
        int f4 = it*256 + t; int r = f4 >> 5, q = f4 & 31;
        *(float4*)&rowbuf[r][q*4] = ht4[(size_t)(row0 + r)*32 + q];
    }
    __syncthreads();

    const int tc = t & 15, rs = t >> 4;
    const float4* bc4 = (const float4*)bcomb;
    float4 c0 = bc4[tc], c1 = bc4[16 + tc];
    float acc[8] = {c0.x,c0.y,c0.z,c0.w,c1.x,c1.y,c1.z,c1.w};
    const float4* WL4 = (const float4*)WL;
    #pragma unroll 8
    for (int d = 0; d < DM; ++d) {
        float a = rowbuf[rs][d];
        float4 b0 = WL4[d*32 + tc], b1 = WL4[d*32 + 16 + tc];
        acc[0] = fmaf(a, b0.x, acc[0]); acc[1] = fmaf(a, b0.y, acc[1]);
        acc[2] = fmaf(a, b0.z, acc[2]); acc[3] = fmaf(a, b0.w, acc[3]);
        acc[4] = fmaf(a, b1.x, acc[4]); acc[5] = fmaf(a, b1.y, acc[5]);
        acc[6] = fmaf(a, b1.z, acc[6]); acc[7] = fmaf(a, b1.w, acc[7]);
    }
    float4* o4 = (float4*)htp;
    float4 o0 = {acc[0],acc[1],acc[2],acc[3]}, o1 = {acc[4],acc[5],acc[6],acc[7]};
    o4[(size_t)(row0 + rs)*32 + tc]      = o0;
    o4[(size_t)(row0 + rs)*32 + 16 + tc] = o1;
}

// ---------------------------------------------------------------------------
// K2 (MFMA + LDS-B + M_rep=2): 1000 blocks x 512 thr (8 waves), 256 rows/blk.
// LDS layout swizzle: chunk(d16, e) stored at d16*128 + ((e + d16) & 127)
// -> staging writes are 2-way bank aliased (free) instead of 16-way
//    (round-9 SQ_LDS_BANK_CONFLICT 3.58M, mostly the d16-fast write pattern).
// Reads apply the same rotation; their bank spread is unchanged (at the
// b128 structural floor of 8 accesses/bank).
// ---------------------------------------------------------------------------
__global__ __launch_bounds__(512, 3)
void k2_energy(const float* __restrict__ factor,
               const unsigned short* __restrict__ WtHi,
               const unsigned short* __restrict__ WtLo,
               const float* __restrict__ wv, const float* __restrict__ htp,
               const int* __restrict__ entn, float* __restrict__ energy) {
    __shared__ unsigned short WL[32768];   // 64KB: hi = chunks 0..2047, lo = 2048..4095
    const int t    = threadIdx.x;
    const int wid  = t >> 6;          // 0..7
    const int lane = t & 63;
    const int c    = lane & 15;       // A-row-in-tile / C-col / B-col index
    const int g16  = lane >> 4;       // k-group / C-row-group
    const int row0 = blockIdx.x * 256 + wid * 32;

    // ---- stage Wt hi/lo -> LDS (16B-chunk transpose + d16-rotation) ----
    // global side: wave reads 1KB contiguous runs (coalesced).
    #pragma unroll
    for (int it = 0; it < 8; ++it) {
        int u = it*512 + t;                 // 0..4095 chunk id
        int m = u & 2047;                   // chunk within one matrix
        int e = m >> 4, d16 = m & 15;
        const unsigned short* src = (it < 4 ? WtHi : WtLo) + (size_t)e*DM + d16*8;
        short8 v = *(const short8*)src;
        int dst = ((it < 4) ? 0 : 2048) + d16*128 + ((e + d16) & 127);
        *(short8*)&WL[(size_t)dst*8] = v;
    }
    __syncthreads();

    f32x4 acc[2][8];
    #pragma unroll
    for (int tile = 0; tile < 2; ++tile)
        #pragma unroll
        for (int nf = 0; nf < 8; ++nf) acc[tile][nf] = (f32x4){0.f,0.f,0.f,0.f};

    float wvv[8];
    #pragma unroll
    for (int nf = 0; nf < 8; ++nf) wvv[nf] = wv[nf*16 + c];

    const float* arow0 = factor + (size_t)(row0 + c)*128;
    const float* arow1 = factor + (size_t)(row0 + 16 + c)*128;

    #pragma unroll
    for (int ks = 0; ks < 4; ++ks) {
        const int off = ks*32 + g16*8;
        float4 a00 = *(const float4*)(arow0 + off);
        float4 a01 = *(const float4*)(arow0 + off + 4);
        float4 a10 = *(const float4*)(arow1 + off);
        float4 a11 = *(const float4*)(arow1 + off + 4);
        float av0[8] = {a00.x,a00.y,a00.z,a00.w,a01.x,a01.y,a01.z,a01.w};
        float av1[8] = {a10.x,a10.y,a10.z,a10.w,a11.x,a11.y,a11.z,a11.w};
        short8 ah0, al0, ah1, al1;
        #pragma unroll
        for (int e = 0; e < 8; ++e) {
            short h, l;
            bf16_split(av0[e], h, l); ah0[e] = h; al0[e] = l;
            bf16_split(av1[e], h, l); ah1[e] = h; al1[e] = l;
        }
        const int d16r = ks*4 + g16;        // k-slice index
        const int cb   = d16r*128;
        #pragma unroll
        for (int nf = 0; nf < 8; ++nf) {
            int ce = (nf*16 + c + d16r) & 127;
            short8 bh = *(const short8*)&WL[(size_t)(cb + ce)*8];
            short8 bl = *(const short8*)&WL[(size_t)(2048 + cb + ce)*8];
            acc[0][nf] = __builtin_amdgcn_mfma_f32_16x16x32_bf16(ah0, bh, acc[0][nf], 0, 0, 0);
            acc[0][nf] = __builtin_amdgcn_mfma_f32_16x16x32_bf16(al0, bh, acc[0][nf], 0, 0, 0);
            acc[0][nf] = __builtin_amdgcn_mfma_f32_16x16x32_bf16(ah0, bl, acc[0][nf], 0, 0, 0);
            acc[1][nf] = __builtin_amdgcn_mfma_f32_16x16x32_bf16(ah1, bh, acc[1][nf], 0, 0, 0);
            acc[1][nf] = __builtin_amdgcn_mfma_f32_16x16x32_bf16(al1, bh, acc[1][nf], 0, 0, 0);
            acc[1][nf] = __builtin_amdgcn_mfma_f32_16x16x32_bf16(ah1, bl, acc[1][nf], 0, 0, 0);
        }
    }

    const int e0 = entn[0], e1n = entn[1], e2n = entn[2], e3 = entn[3];

    #pragma unroll
    for (int tile = 0; tile < 2; ++tile) {
        #pragma unroll
        for (int e = 0; e < 4; ++e) {
            int rg  = row0 + tile*16 + g16*4 + e;   // global row this lane holds
            int bi  = rg / NROW_BI;
            int rem = rg - bi*NROW_BI;
            int j = rem / NE;
            int k = rem - j*NE;
            const float* h1 = htp + (size_t)(bi*NE + j)*DM;
            const float* h2 = htp + (size_t)(bi*NE + k)*DM;
            float p1 = 0.0f, p2 = 0.0f;
            #pragma unroll
            for (int nf = 0; nf < 8; ++nf) {
                float cc = acc[tile][nf][e];
                float v1 = h1[nf*16 + c];
                float v2 = h2[nf*16 + c];
                p1 = fmaf(wvv[nf], gelu_fast(cc + v1), p1);
                p2 = fmaf(wvv[nf], gelu_fast(cc + v2), p2);
            }
            p1 += __shfl_xor(p1, 1); p2 += __shfl_xor(p2, 1);
            p1 += __shfl_xor(p1, 2); p2 += __shfl_xor(p2, 2);
            p1 += __shfl_xor(p1, 4); p2 += __shfl_xor(p2, 4);
            p1 += __shfl_xor(p1, 8); p2 += __shfl_xor(p2, 8);
            if (c == 0) {
                int b = bi / NE, i = bi - b*NE;
                int en = (b == 0) ? e0 : (b == 1) ? e1n : (b == 2) ? e2n : e3;
                bool msk = (j == k) || !((i < en) && (j < en) && (k < en));
                float v1 = msk ? -10000.0f : p1;
                float v2 = msk ? -10000.0f : p2;
                energy[(size_t)(bi*NE + j)*NE2 + k]       = v1;
                energy[(size_t)(bi*NE + k)*NE2 + NE + j]  = v2;
            }
        }
    }
}

// ---------------------------------------------------------------------------
// K3: per (b,i,j): softmax over 80 energies, then weighted factor sum.
// ---------------------------------------------------------------------------
__global__ __launch_bounds__(64)
void k3_attn_av(const float* __restrict__ energy, const float* __restrict__ factor,
                float* __restrict__ av) {
    __shared__ float att[NE2];
    const int l = threadIdx.x;
    const int gid = blockIdx.x;
    const int bi = gid % BI_CNT;
    const int j  = gid / BI_CNT;

    const float* eb = energy + (size_t)(bi*NE + j)*NE2;
    float ea = eb[l];
    float ebv = (l < 16) ? eb[64 + l] : -INFINITY;
    float m = fmaxf(ea, ebv);
    m = fmaxf(m, __shfl_xor(m, 1));  m = fmaxf(m, __shfl_xor(m, 2));
    m = fmaxf(m, __shfl_xor(m, 4));  m = fmaxf(m, __shfl_xor(m, 8));
    m = fmaxf(m, __shfl_xor(m, 16)); m = fmaxf(m, __shfl_xor(m, 32));
    float x1 = expf(ea - m);
    float x2 = (l < 16) ? expf(ebv - m) : 0.0f;
    float s = x1 + x2;
    s += __shfl_xor(s, 1);  s += __shfl_xor(s, 2);
    s += __shfl_xor(s, 4);  s += __shfl_xor(s, 8);
    s += __shfl_xor(s, 16); s += __shfl_xor(s, 32);
    att[l] = x1 / s;
    if (l < 16) att[64 + l] = x2 / s;
    __syncthreads();

    float av0 = 0.0f, av1 = 0.0f;
    const float* f1 = factor + (size_t)(bi*NROW_BI + j*NE)*128;
    #pragma unroll 8
    for (int k = 0; k < NE; ++k) {
        float w = att[k];
        av0 = fmaf(w, f1[k*128 + l],      av0);
        av1 = fmaf(w, f1[k*128 + 64 + l], av1);
    }
    const float* f2 = factor + (size_t)(bi*NROW_BI + j)*128;
    #pragma unroll 8
    for (int q = 0; q < NE; ++q) {
        float w = att[NE + q];
        av0 = fmaf(w, f2[(size_t)q*NE*128 + l],      av0);
        av1 = fmaf(w, f2[(size_t)q*NE*128 + 64 + l], av1);
    }
    float* o = av + (size_t)(bi*NE + j)*128;
    o[l] = av0; o[64 + l] = av1;
}

// ---------------------------------------------------------------------------
// K4: out = LN(av @ W_fc + b_fc + ht) * scale + bias.
// ---------------------------------------------------------------------------
__global__ __launch_bounds__(256, 2)
void k4_out(const float* __restrict__ av, const float* __restrict__ Wfc,
            const float* __restrict__ bfc, const float* __restrict__ ht,
            const float* __restrict__ lns, const float* __restrict__ lnb,
            float* __restrict__ out) {
    __shared__ float WL[DM*DR];
    __shared__ float rowbuf[16][132];
    const int t = threadIdx.x;
    const int row0 = blockIdx.x * 16;

    const float4* W4 = (const float4*)Wfc;
    float4* WL4s = (float4*)WL;
    #pragma unroll
    for (int it = 0; it < 16; ++it) WL4s[it*256 + t] = W4[it*256 + t];
    const float4* av4 = (const float4*)av;
    #pragma unroll
    for (int it = 0; it < 2; ++it) {
        int f4 = it*256 + t; int r = f4 >> 5, q = f4 & 31;
        *(float4*)&rowbuf[r][q*4] = av4[(size_t)(row0 + r)*32 + q];
    }
    __syncthreads();

    const int tc = t & 15, rs = t >> 4;
    const int row = row0 + rs;
    const float4* bf4 = (const float4*)bfc;
    float4 c0 = bf4[tc], c1 = bf4[16 + tc];
    float acc[8] = {c0.x,c0.y,c0.z,c0.w,c1.x,c1.y,c1.z,c1.w};
    const float4* WL4 = (const float4*)WL;
    #pragma unroll 8
    for (int d = 0; d < DM; ++d) {
        float a = rowbuf[rs][d];
        float4 b0 = WL4[d*32 + tc], b1 = WL4[d*32 + 16 + tc];
        acc[0] = fmaf(a, b0.x, acc[0]); acc[1] = fmaf(a, b0.y, acc[1]);
        acc[2] = fmaf(a, b0.z, acc[2]); acc[3] = fmaf(a, b0.w, acc[3]);
        acc[4] = fmaf(a, b1.x, acc[4]); acc[5] = fmaf(a, b1.y, acc[5]);
        acc[6] = fmaf(a, b1.z, acc[6]); acc[7] = fmaf(a, b1.w, acc[7]);
    }
    const float4* ht4 = (const float4*)ht;
    float4 ha = ht4[(size_t)row*32 + tc], hb = ht4[(size_t)row*32 + 16 + tc];
    float o[8];
    o[0] = acc[0] + ha.x; o[1] = acc[1] + ha.y; o[2] = acc[2] + ha.z; o[3] = acc[3] + ha.w;
    o[4] = acc[4] + hb.x; o[5] = acc[5] + hb.y; o[6] = acc[6] + hb.z; o[7] = acc[7] + hb.w;

    float s1 = o[0]+o[1]+o[2]+o[3]+o[4]+o[5]+o[6]+o[7];
    s1 += __shfl_xor(s1, 1); s1 += __shfl_xor(s1, 2);
    s1 += __shfl_xor(s1, 4); s1 += __shfl_xor(s1, 8);
    float mu = s1 * (1.0f/128.0f);
    float s2 = 0.0f;
    #pragma unroll
    for (int jj = 0; jj < 8; ++jj) { float d = o[jj] - mu; s2 = fmaf(d, d, s2); }
    s2 += __shfl_xor(s2, 1); s2 += __shfl_xor(s2, 2);
    s2 += __shfl_xor(s2, 4); s2 += __shfl_xor(s2, 8);
    float var = s2 * (1.0f/128.0f);
    float rstd = 1.0f / sqrtf(var + 1e-6f);

    const float4* sc4 = (const float4*)lns;
    const float4* bs4 = (const float4*)lnb;
    float4 sa = sc4[tc], sb = sc4[16 + tc];
    float4 ba = bs4[tc], bb = bs4[16 + tc];
    float4 r0, r1;
    r0.x = (o[0]-mu)*rstd*sa.x + ba.x; r0.y = (o[1]-mu)*rstd*sa.y + ba.y;
    r0.z = (o[2]-mu)*rstd*sa.z + ba.z; r0.w = (o[3]-mu)*rstd*sa.w + ba.w;
    r1.x = (o[4]-mu)*rstd*sb.x + bb.x; r1.y = (o[5]-mu)*rstd*sb.y + bb.y;
    r1.z = (o[6]-mu)*rstd*sb.z + bb.z; r1.w = (o[7]-mu)*rstd*sb.w + bb.w;
    float4* o4 = (float4*)out;
    o4[(size_t)row*32 + tc]      = r0;
    o4[(size_t)row*32 + 16 + tc] = r1;
}

// ---------------------------------------------------------------------------
extern "C" void kernel_launch(void* const* d_in, const int* in_sizes, int n_in,
                              void* d_out, int out_size, void* d_ws, size_t ws_size,
                              hipStream_t stream) {
    const float* ht     = (const float*)d_in[0];
    const float* factor = (const float*)d_in[1];
    const int*   entn   = (const int*)  d_in[2];
    const float* Wcomb  = (const float*)d_in[3];
    const float* bcomb  = (const float*)d_in[4];
    const float* wv     = (const float*)d_in[5];
    const float* Wfc    = (const float*)d_in[6];
    const float* bfc    = (const float*)d_in[7];
    const float* lns    = (const float*)d_in[8];
    const float* lnb    = (const float*)d_in[9];
    float* out = (float*)d_out;

    char* ws = (char*)d_ws;
    float* htp    = (float*)(ws);                       // 6400*128*4 = 3,276,800 B
    float* energy = (float*)(ws + 3276800);             // 6400*80*4  = 2,048,000 B
    float* av     = (float*)(ws + 3276800 + 2048000);   // 6400*128*4 = 3,276,800 B
    // WtHi/WtLo live in the av region (64KB << 3.3MB): K0 writes, K2 reads,
    // K3 overwrites av only after K2 completes (same stream).
    unsigned short* WtHi = (unsigned short*)av;
    unsigned short* WtLo = (unsigned short*)(av + 16384);

    k0_wprep<<<dim3(64),      dim3(256), 0, stream>>>(Wcomb, WtHi, WtLo);
    k1_htproj<<<dim3(NBIJ/16),dim3(256), 0, stream>>>(ht, Wcomb, bcomb, htp);
    k2_energy<<<dim3(1000),   dim3(512), 0, stream>>>(factor, WtHi, WtLo, wv, htp, entn, energy);
    k3_attn_av<<<dim3(NBIJ),  dim3(64),  0, stream>>>(energy, factor, av);
    k4_out<<<dim3(NBIJ/16),   dim3(256), 0, stream>>>(av, Wfc, bfc, ht, lns, lnb, out);
}